// Round 2
// baseline (65.024 us; speedup 1.0000x reference)
//
#include <hip/hip_runtime.h>

// FM forward on MI355X — 16 lanes per batch row (one lane per emb element).
// Shapes: x_num (8192,3) f32, x_cat (8192,4) i32, v (18183,16) f32,
// global_bias (1,) f32, num_bias (3,) f32, cat_bias (18180,) f32.
// Output: (8192,1) f32.
//
// Math per row b:
//   idx_j = x_cat[b,j] + offset_j, offsets = {0,10000,18000,18100}
//   bias  = gb + sum_j xn_j*nb_j + sum_j cbias[idx_j]
//   s[e]  = sum_j xn_j * v[j,e] + sum_j v[3+idx_j, e]
//   ss[e] = sum_j (xn_j*v[j,e])^2 + sum_j v[3+idx_j,e]^2
//   y = bias + 0.5 * sum_e (s[e]^2 - ss[e])
//
// Kernel-side is latency/instruction bound (hot footprint ~320 v-rows =
// 20 KB, L1-resident; ideal traffic ~2.5 MB -> sub-µs at BW ceiling), so:
//  - x_cat loaded as a single int4 (16B-aligned: b*16 bytes)
//  - all v/cbias indexing in 32-bit (max offset ~291K) -> no 64-bit addr chains
//  - the 4 cbias gathers are spread over lanes 0..3 and folded into the
//    wave reduction as 2*cbias (the final *0.5 recovers them) instead of a
//    serial 4-load tail on lane 0
//  - grid divides batch exactly -> no bounds branch

#define FM_BATCH 8192

__global__ __launch_bounds__(256) void fm_fwd_kernel(
    const float* __restrict__ x_num,
    const int*   __restrict__ x_cat,
    const float* __restrict__ v,
    const float* __restrict__ gbias,
    const float* __restrict__ nbias,
    const float* __restrict__ cbias,
    float*       __restrict__ out)
{
    const int tid = blockIdx.x * 256 + threadIdx.x;
    const int b = tid >> 4;        // batch row
    const int e = tid & 15;        // embedding element

    // one 16B vector load for the 4 categorical ids (broadcast across lanes)
    const int4 ic = *reinterpret_cast<const int4*>(x_cat + b * 4);
    const int i0 = ic.x;            // + 0
    const int i1 = ic.y + 10000;
    const int i2 = ic.z + 18000;
    const int i3 = ic.w + 18100;

    // numeric features: same-address broadcast within the 16-lane group
    const float xn0 = x_num[b * 3 + 0];
    const float xn1 = x_num[b * 3 + 1];
    const float xn2 = x_num[b * 3 + 2];

    // numeric rows 0..2 (L1-hot) + 4 gathered categorical rows, 32-bit offsets
    const float a0 = v[e];
    const float a1 = v[16 + e];
    const float a2 = v[32 + e];
    const float c0 = v[(3 + i0) * 16 + e];
    const float c1 = v[(3 + i1) * 16 + e];
    const float c2 = v[(3 + i2) * 16 + e];
    const float c3 = v[(3 + i3) * 16 + e];

    const float t0 = xn0 * a0, t1 = xn1 * a1, t2 = xn2 * a2;
    const float s  = t0 + t1 + t2 + c0 + c1 + c2 + c3;
    const float ss = t0 * t0 + t1 * t1 + t2 * t2
                   + c0 * c0 + c1 * c1 + c2 * c2 + c3 * c3;
    float part = s * s - ss;

    // fold the categorical bias lookups into the reduction: lane j (j<4)
    // adds 2*cbias[idx_j]; the final *0.5 turns it back into +cbias[idx_j].
    if (e < 4) {
        const int gid = (e == 1) ? i1 : (e == 2) ? i2 : (e == 3) ? i3 : i0;
        part += 2.0f * cbias[gid];
    }

    // reduce over the 16 lanes of this row (stays inside the wave)
    part += __shfl_xor(part, 1, 64);
    part += __shfl_xor(part, 2, 64);
    part += __shfl_xor(part, 4, 64);
    part += __shfl_xor(part, 8, 64);

    if (e == 0) {
        // gbias/nbias are wave-uniform addresses -> scalar loads
        const float bias = gbias[0]
                         + xn0 * nbias[0] + xn1 * nbias[1] + xn2 * nbias[2];
        out[b] = bias + 0.5f * part;
    }
}

extern "C" void kernel_launch(void* const* d_in, const int* in_sizes, int n_in,
                              void* d_out, int out_size, void* d_ws, size_t ws_size,
                              hipStream_t stream)
{
    const float* x_num = (const float*)d_in[0];
    const int*   x_cat = (const int*)  d_in[1];
    const float* v     = (const float*)d_in[2];
    const float* gb    = (const float*)d_in[3];
    const float* nb    = (const float*)d_in[4];
    const float* cb    = (const float*)d_in[5];
    float*       out   = (float*)d_out;

    const int threads = FM_BATCH * 16;          // 16 lanes per row
    const int block   = 256;
    const int grid    = threads / block;        // 512 blocks, exact
    fm_fwd_kernel<<<grid, block, 0, stream>>>(x_num, x_cat, v, gb, nb, cb, out);
}